// Round 17
// baseline (119.859 us; speedup 1.0000x reference)
//
#include <hip/hip_runtime.h>
#include <hip/hip_bf16.h>

// BCNet fused pipeline, MI355X gfx950 — round 17.
// cvt_qw deleted: K1's GEMM reads q/Wq as f32 directly (reg-staged convert +
// both-sides swizzled ds_write). Everything else = R16 (proven best).
//   K1f: blocks 0-223: q_ = relu(q @ Wq^T + bq) [f32 in]; blocks 224-511: cvt v,Wv,W2
//   K2: qw[128,2048] = sum_q q_[b*14+q,:] * wh[q]
//   K3: logits = relu(vb @ Wvb^T + bv) * qw + bh       (192x256 8-phase)
//   K4: out = logits @ W2b^T + b2                      (192x256 8-phase)

typedef __attribute__((ext_vector_type(4))) float f32x4;
typedef __attribute__((ext_vector_type(8))) short short8;

__device__ __forceinline__ short f2bf(float f) {
    union { float f; unsigned u; } x; x.f = f;
    unsigned u = x.u;
    unsigned r = (u + 0x7FFFu + ((u >> 16) & 1u)) >> 16;   // RN-even
    return (short)(r & 0xFFFFu);
}
__device__ __forceinline__ float bf2f(short s) {
    union { unsigned u; float f; } x; x.u = ((unsigned)(unsigned short)s) << 16;
    return x.f;
}

__device__ __forceinline__ void gload_lds16(const short* g, short* l) {
    __builtin_amdgcn_global_load_lds(
        (const __attribute__((address_space(1))) unsigned int*)g,
        (__attribute__((address_space(3))) unsigned int*)l,
        16, 0, 0);
}

__device__ __forceinline__ void cvt_chunk(const float* __restrict__ src,
                                          short* __restrict__ dst, int i)
{
    f32x4 a = *(const f32x4*)&src[i];
    f32x4 b = *(const f32x4*)&src[i + 4];
    short8 s;
    #pragma unroll
    for (int j = 0; j < 4; ++j) { s[j] = f2bf(a[j]); s[4 + j] = f2bf(b[j]); }
    *(short8*)&dst[i] = s;
}

// ---------------- K1 fused: 128² BK=64 GEMM, f32 inputs (blocks 0..223) + cvt (224..511) ----------------
// GEMM: q_[1792,2048] = relu(q[1792,1024] @ Wq[2048,1024]^T + bq) -> bf16
// Staging: reg-staged f32 load + f2bf + swizzled ds_write (element (r,c) at
// byte r*128 + (2c ^ ((r&7)<<4)) — same involution the readers use).
#define V_CH  1179648                 // 4608*2048/8
#define WV_CH 524288                  // 2048*2048/8
#define W2_CH 524288
__global__ __launch_bounds__(256)
void k1_fused(const float* __restrict__ Af, const float* __restrict__ Bf,
              const float* __restrict__ bias, short* __restrict__ Cp,
              const float* __restrict__ v,  short* __restrict__ vb,
              const float* __restrict__ Wv, short* __restrict__ Wvb,
              const float* __restrict__ W2, short* __restrict__ W2b)
{
    __shared__ short ldsA[128 * 64];
    __shared__ short ldsB[128 * 64];

    if (blockIdx.x >= 224) {
        const int total = V_CH + WV_CH + W2_CH;
        const int stride = 288 * 256;
        for (int c = (blockIdx.x - 224) * 256 + threadIdx.x; c < total; c += stride) {
            if      (c < V_CH)         cvt_chunk(v,  vb,  c * 8);
            else if (c < V_CH + WV_CH) cvt_chunk(Wv, Wvb, (c - V_CH) * 8);
            else                       cvt_chunk(W2, W2b, (c - V_CH - WV_CH) * 8);
        }
        return;
    }

    const int K = 1024, N = 2048;
    const int tid    = threadIdx.x;
    const int lane   = tid & 63;
    const int wid    = tid >> 6;
    const int wr     = wid >> 1;
    const int wc     = wid & 1;
    const int lrow   = lane & 15;
    const int lchunk = lane >> 4;

    const int row0 = (blockIdx.x % 14) * 128;
    const int col0 = (blockIdx.x / 14) * 128;

    // staging lane constants: rows wid*32 + i*8 + s8, elem cols st_c..st_c+7
    const int s8   = lane >> 3;              // 0..7 == (row & 7)
    const int st_c = (lane & 7) * 8;         // 0..56

    f32x4 acc[4][4];
    #pragma unroll
    for (int i = 0; i < 4; ++i)
        #pragma unroll
        for (int j = 0; j < 4; ++j)
            acc[i][j] = (f32x4)0.0f;

    const int nk = K >> 6;

    f32x4 R[4][4];   // [i][ A0 A1 B0 B1 ]

    auto loadreg = [&](int kt) {
        const int kc = kt * 64 + st_c;
        #pragma unroll
        for (int i = 0; i < 4; ++i) {
            const int r = wid * 32 + i * 8 + s8;
            R[i][0] = *(const f32x4*)&Af[(size_t)(row0 + r) * K + kc];
            R[i][1] = *(const f32x4*)&Af[(size_t)(row0 + r) * K + kc + 4];
            R[i][2] = *(const f32x4*)&Bf[(size_t)(col0 + r) * K + kc];
            R[i][3] = *(const f32x4*)&Bf[(size_t)(col0 + r) * K + kc + 4];
        }
    };
    auto storelds = [&]() {
        #pragma unroll
        for (int i = 0; i < 4; ++i) {
            short8 sa, sb;
            #pragma unroll
            for (int j = 0; j < 4; ++j) {
                sa[j] = f2bf(R[i][0][j]); sa[4 + j] = f2bf(R[i][1][j]);
                sb[j] = f2bf(R[i][2][j]); sb[4 + j] = f2bf(R[i][3][j]);
            }
            const int byte = (wid * 32 + i * 8 + s8) * 128 + ((st_c * 2) ^ (s8 << 4));
            *(short8*)((char*)ldsA + byte) = sa;
            *(short8*)((char*)ldsB + byte) = sb;
        }
    };

    loadreg(0);
    for (int kt = 0; kt < nk; ++kt) {
        if (kt) __syncthreads();          // readers done with previous tile
        storelds();
        __syncthreads();                  // staged tile visible
        if (kt + 1 < nk) loadreg(kt + 1); // prefetch next f32 tile (overlaps compute)

        short8 af[4][2], bfv[4][2];
        #pragma unroll
        for (int mi = 0; mi < 4; ++mi) {
            const int row = wr * 64 + mi * 16 + lrow;
            #pragma unroll
            for (int ks = 0; ks < 2; ++ks)
                af[mi][ks] = *(const short8*)((const char*)ldsA +
                    row * 128 + (((ks * 4 + lchunk) * 16) ^ ((row & 7) << 4)));
        }
        #pragma unroll
        for (int ni = 0; ni < 4; ++ni) {
            const int row = wc * 64 + ni * 16 + lrow;
            #pragma unroll
            for (int ks = 0; ks < 2; ++ks)
                bfv[ni][ks] = *(const short8*)((const char*)ldsB +
                    row * 128 + (((ks * 4 + lchunk) * 16) ^ ((row & 7) << 4)));
        }
        #pragma unroll
        for (int ks = 0; ks < 2; ++ks)
            #pragma unroll
            for (int mi = 0; mi < 4; ++mi)
                #pragma unroll
                for (int ni = 0; ni < 4; ++ni)
                    acc[mi][ni] = __builtin_amdgcn_mfma_f32_16x16x32_bf16(
                        af[mi][ks], bfv[ni][ks], acc[mi][ni], 0, 0, 0);
    }

    #pragma unroll
    for (int mi = 0; mi < 4; ++mi)
        #pragma unroll
        for (int ni = 0; ni < 4; ++ni)
            #pragma unroll
            for (int r = 0; r < 4; ++r) {
                const int row = row0 + wr * 64 + mi * 16 + lchunk * 4 + r;
                const int col = col0 + wc * 64 + ni * 16 + lrow;
                float val = fmaxf(acc[mi][ni][r] + bias[col], 0.0f);
                Cp[(size_t)row * N + col] = f2bf(val);
            }
}

// ---------------- 192x256 8-phase pipelined GEMM (K3/K4) — R16 proven ----------------
template<int EPI>
__global__ __launch_bounds__(512, 2)
void gemm256(const short* __restrict__ Ab, const short* __restrict__ Bb,
             const float* __restrict__ bias, const float* __restrict__ qw,
             const float* __restrict__ bh_p, void* __restrict__ Cp,
             int M, int N, int K)
{
    __shared__ short lds[2][4][128 * 64];   // 128 KiB

    const int tid  = threadIdx.x;
    const int lane = tid & 63;
    const int w    = tid >> 6;
    const int wr   = w >> 2;
    const int wc   = w & 3;
    const int fr   = lane & 15;
    const int fc   = lane >> 4;

    const int row0 = blockIdx.x * 192;
    const int col0 = blockIdx.y * 256;

    const int sl_s = lane >> 3;
    const int sl_c = ((lane & 7) ^ sl_s) * 8;

    const int nt = K >> 6;

    f32x4 acc[6][4];
    #pragma unroll
    for (int i = 0; i < 6; ++i)
        #pragma unroll
        for (int j = 0; j < 4; ++j)
            acc[i][j] = (f32x4)0.0f;

    auto stageA = [&](int t, int q) {
        #pragma unroll
        for (int i = 0; i < 2; ++i) {
            const int g  = w * 2 + i;
            const int rl = g * 8 + sl_s;
            const int srow = (rl < 96)
                ? row0 + (rl / 48) * 96 + q * 48 + (rl % 48)
                : row0;                                 // pad, never read
            gload_lds16(&Ab[(size_t)srow * K + t * 64 + sl_c],
                        &lds[t & 1][q][g * 512]);
        }
    };
    auto stageB = [&](int t, int q) {
        #pragma unroll
        for (int i = 0; i < 2; ++i) {
            const int g  = w * 2 + i;
            const int rl = g * 8 + sl_s;
            const int srow = col0 + (rl >> 5) * 64 + q * 32 + (rl & 31);
            gload_lds16(&Bb[(size_t)srow * K + t * 64 + sl_c],
                        &lds[t & 1][2 + q][g * 512]);
        }
    };

    short8 A0[3][2], A1[3][2], B0[2][2], B1[2][2];

#define READA(T, MQ, DST)                                                       \
    _Pragma("unroll") for (int m_ = 0; m_ < 3; ++m_) {                          \
        const int rl_ = wr * 48 + m_ * 16 + fr;                                 \
        _Pragma("unroll") for (int k_ = 0; k_ < 2; ++k_)                        \
            DST[m_][k_] = *(const short8*)((const char*)&lds[(T) & 1][MQ][0]    \
                + rl_ * 128 + ((k_ * 64 + fc * 16) ^ ((rl_ & 7) << 4)));        \
    }
#define READB(T, NQ, DST)                                                       \
    _Pragma("unroll") for (int n_ = 0; n_ < 2; ++n_) {                          \
        const int rl_ = wc * 32 + n_ * 16 + fr;                                 \
        _Pragma("unroll") for (int k_ = 0; k_ < 2; ++k_)                        \
            DST[n_][k_] = *(const short8*)((const char*)&lds[(T) & 1][2 + (NQ)][0] \
                + rl_ * 128 + ((k_ * 64 + fc * 16) ^ ((rl_ & 7) << 4)));        \
    }
#define MFMAQ(MQ, NQ, ASET, BSET)                                               \
    _Pragma("unroll") for (int m_ = 0; m_ < 3; ++m_)                            \
      _Pragma("unroll") for (int n_ = 0; n_ < 2; ++n_)                          \
        _Pragma("unroll") for (int k_ = 0; k_ < 2; ++k_)                        \
          acc[(MQ) * 3 + m_][(NQ) * 2 + n_] =                                   \
              __builtin_amdgcn_mfma_f32_16x16x32_bf16(                          \
                  ASET[m_][k_], BSET[n_][k_], acc[(MQ) * 3 + m_][(NQ) * 2 + n_], 0, 0, 0);

#define BAR()   asm volatile("s_barrier" ::: "memory")
#define PRIO1() __builtin_amdgcn_s_setprio(1)
#define PRIO0() __builtin_amdgcn_s_setprio(0)
#define VM4()   asm volatile("s_waitcnt vmcnt(4)" ::: "memory")
#define VM0()   asm volatile("s_waitcnt vmcnt(0)" ::: "memory")

#define KITER(T0, T1, ST1, ST2, ST3, ST4, ST5, ST6, ST7, ST8, D4, D8)           \
  {                                                                             \
    READA(T0, 0, A0); READB(T0, 0, B0);                                         \
    PRIO1(); MFMAQ(0, 0, A0, B0); PRIO0();                                      \
    READB(T0, 1, B1); ST1; BAR();                                               \
    PRIO1(); MFMAQ(0, 1, A0, B1); PRIO0();                                      \
    READA(T0, 1, A1); ST2; BAR();                                               \
    PRIO1(); MFMAQ(1, 1, A1, B1); PRIO0();                                      \
    ST3; BAR();                                                                 \
    PRIO1(); MFMAQ(1, 0, A1, B0); PRIO0();                                      \
    ST4; D4; BAR();                                                             \
    READA(T1, 0, A0); READB(T1, 0, B0);                                         \
    PRIO1(); MFMAQ(0, 0, A0, B0); PRIO0();                                      \
    READB(T1, 1, B1); ST5; BAR();                                               \
    PRIO1(); MFMAQ(0, 1, A0, B1); PRIO0();                                      \
    READA(T1, 1, A1); ST6; BAR();                                               \
    PRIO1(); MFMAQ(1, 1, A1, B1); PRIO0();                                      \
    ST7; BAR();                                                                 \
    PRIO1(); MFMAQ(1, 0, A1, B0); PRIO0();                                      \
    ST8; D8; BAR();                                                             \
  }

    // prologue
    stageA(0, 0); stageB(0, 0); stageB(0, 1); stageA(0, 1);
    stageA(1, 0); stageB(1, 1);
    VM4();
    BAR();

    const int niter = (nt >> 1) - 1;
    for (int j = 0; j < niter; ++j) {
        const int t0 = 2 * j, t1 = 2 * j + 1;
        KITER(t0, t1,
              stageA(t1, 1),     stageB(t1, 0),
              stageA(t0 + 2, 0), stageB(t0 + 2, 1),
              stageA(t0 + 2, 1), stageB(t0 + 2, 0),
              stageA(t1 + 2, 0), stageB(t1 + 2, 1),
              VM4(), VM4());
    }
    // tail
    {
        const int t0 = nt - 2, t1 = nt - 1;
        KITER(t0, t1,
              stageA(t1, 1), stageB(t1, 0),
              (void)0, (void)0, (void)0, (void)0, (void)0, (void)0,
              VM0(), (void)0);
    }

#undef KITER
#undef READA
#undef READB
#undef MFMAQ
#undef BAR
#undef PRIO1
#undef PRIO0
#undef VM4
#undef VM0

    const float bhv = (EPI == 1) ? bh_p[0] : 0.0f;
    #pragma unroll
    for (int m = 0; m < 6; ++m) {
        #pragma unroll
        for (int n = 0; n < 4; ++n) {
            #pragma unroll
            for (int r = 0; r < 4; ++r) {
                const int row = row0 + wr * 96 + m * 16 + fc * 4 + r;
                const int col = col0 + wc * 64 + n * 16 + fr;
                float val = acc[m][n][r];
                if (EPI == 1) {
                    val = fmaxf(val + bias[col], 0.0f);
                    const int b = row / 36;
                    val = val * qw[b * 2048 + col] + bhv;
                    ((short*)Cp)[(size_t)row * N + col] = f2bf(val);
                } else {
                    ((float*)Cp)[(size_t)row * N + col] = val + bias[col];
                }
            }
        }
    }
}

// qw[b,h] = sum_q bf2f(q_[b*14+q, h]) * wh[q]
__global__ __launch_bounds__(256)
void qw_reduce(const short* __restrict__ q_, const float* __restrict__ wh,
               float* __restrict__ qw)
{
    const int idx = blockIdx.x * 256 + threadIdx.x;
    const int b = idx >> 11;
    const int h = idx & 2047;
    float s = 0.0f;
    #pragma unroll
    for (int qq = 0; qq < 14; ++qq)
        s += bf2f(q_[(size_t)(b * 14 + qq) * 2048 + h]) * wh[qq];
    qw[idx] = s;
}

extern "C" void kernel_launch(void* const* d_in, const int* in_sizes, int n_in,
                              void* d_out, int out_size, void* d_ws, size_t ws_size,
                              hipStream_t stream)
{
    const float* v  = (const float*)d_in[0];
    const float* q  = (const float*)d_in[1];
    const float* Wv = (const float*)d_in[2];
    const float* bv = (const float*)d_in[3];
    const float* Wq = (const float*)d_in[4];
    const float* bq = (const float*)d_in[5];
    const float* wh = (const float*)d_in[6];
    const float* bh = (const float*)d_in[7];
    const float* W2 = (const float*)d_in[8];
    const float* b2 = (const float*)d_in[9];
    float* out = (float*)d_out;

    char* ws = (char*)d_ws;
    short* vb     = (short*)(ws);                  // 4608*2048*2 = 18,874,368
    short* Wvb    = (short*)(ws + 18874368);       // 2048*2048*2 =  8,388,608
    short* W2b    = (short*)(ws + 27262976);       // 2048*2048*2 =  8,388,608
    short* q_ws   = (short*)(ws + 35651584);       // 1792*2048*2 =  7,340,032
    float* qw     = (float*)(ws + 42991616);       // 128*2048*4  =  1,048,576
    short* logits = (short*)(ws + 44040192);       // 4608*2048*2 = 18,874,368
    // total: 62,914,560 B

    // K1 fused: GEMM with f32 inputs (224 blocks) + cvt of v/Wv/W2 (288 blocks)
    k1_fused<<<512, 256, 0, stream>>>(q, Wq, bq, q_ws,
                                      v, vb, Wv, Wvb, W2, W2b);

    // K2: qw reduce
    qw_reduce<<<(128 * 2048) / 256, 256, 0, stream>>>(q_ws, wh, qw);

    // K3: logits = relu(vb @ Wvb^T + bv) * qw + bh
    gemm256<1><<<dim3(4608 / 192, 2048 / 256), 512, 0, stream>>>(
        vb, Wvb, bv, qw, bh, logits, 4608, 2048, 2048);

    // K4: out = logits @ W2b^T + b2
    gemm256<2><<<dim3(4608 / 192, 2048 / 256), 512, 0, stream>>>(
        logits, W2b, b2, nullptr, nullptr, out, 4608, 2048, 2048);
}